// Round 1
// baseline (39.747 us; speedup 1.0000x reference)
//
#include <hip/hip_runtime.h>
#include <cstdint>

#define DIM 64

__global__ __launch_bounds__(256) void disc_kernel(
    const int* __restrict__ node_idx,
    const int* __restrict__ rel_idx,
    const int* __restrict__ nb_idx,
    const float* __restrict__ node_table,
    const float* __restrict__ rel_table,
    float* __restrict__ out, int B)
{
    int lane = threadIdx.x & 63;
    int wid = (blockIdx.x * blockDim.x + threadIdx.x) >> 6;
    // wid is uniform across the wave (consecutive threadIdx.x >> 6);
    // force SGPR so index loads + m-row loads scalarize (s_load).
    wid = __builtin_amdgcn_readfirstlane(wid);
    if (wid >= B) return;

    int ni = node_idx[wid];
    int ri = rel_idx[wid];
    int mi = nb_idx[wid];

    const float* mrow = node_table + (size_t)ni * DIM;          // wave-uniform ptr
    const float* Rm   = rel_table  + (size_t)ri * (DIM * DIM);  // wave-uniform ptr
    const float* nrow = node_table + (size_t)mi * DIM;

    float nv = nrow[lane];      // coalesced 256B wave read

    // temp[lane] = sum_d m[d] * R[d][lane]; each iteration's R read is a
    // contiguous, coalesced 256B wave read; m[d] is a scalar (SGPR) operand.
    float acc = 0.f;
#pragma unroll
    for (int d = 0; d < DIM; ++d) {
        acc = fmaf(mrow[d], Rm[d * DIM + lane], acc);
    }

    float p = acc * nv;
#pragma unroll
    for (int off = 32; off; off >>= 1)
        p += __shfl_xor(p, off, 64);

    if (lane == 0)
        out[wid] = 1.0f / (1.0f + __expf(-p));
}

extern "C" void kernel_launch(void* const* d_in, const int* in_sizes, int n_in,
                              void* d_out, int out_size, void* d_ws, size_t ws_size,
                              hipStream_t stream) {
    const int*   node_idx   = (const int*)d_in[0];
    const int*   rel_idx    = (const int*)d_in[1];
    const int*   nb_idx     = (const int*)d_in[2];
    const float* node_table = (const float*)d_in[3];
    const float* rel_table  = (const float*)d_in[4];
    float* out = (float*)d_out;

    int B = in_sizes[0];                       // 65536
    int threads = 256;                         // 4 waves/block, 1 wave per b
    int blocks = (B * 64 + threads - 1) / threads;
    disc_kernel<<<blocks, threads, 0, stream>>>(node_idx, rel_idx, nb_idx,
                                                node_table, rel_table, out, B);
}